// Round 1
// baseline (746.552 us; speedup 1.0000x reference)
//
#include <hip/hip_runtime.h>

// ---------------------------------------------------------------------------
// GGNN message passing, MI355X/gfx950.
//
// Math refactor:
//   msgs[e] = W[t_e] @ h[src_e] + b[t_e]
//   agg[n]  = sum_{e: dst=n} msgs[e]
//           = scatter_add( Y[src_e, t_e, :] ) + sum_t cnt[n,t]*b_t
//   where Y[n,t,:] = W_t @ h[n]   <- ONE GEMM [50000,128]@[128,512] (6.55 GF)
//   (vs 20.5 GF of per-edge matvecs in the reference formulation)
//
//   GRU: r=sig(i_r+h_r), z=sig(i_z+h_z), n=tanh(i_n + r*h_n)
//   -> single K=256 GEMM: A=[aggb|h], B rows (per out col j):
//      4j+0: [w_ih[j]     | w_hh[j]    ]  (r pre-act, biases added later)
//      4j+1: [w_ih[128+j] | w_hh[128+j]]  (z pre-act)
//      4j+2: [w_ih[256+j] | 0          ]  (i_n)
//      4j+3: [0           | w_hh[256+j]]  (h_n)
//   Output G[n, 4j..4j+3] gate-interleaved -> gates kernel reads 8B/elem.
//
// Precision: bf16 MFMA (fp32 accum) for GEMMs; fp32 atomics for scatter.
// ---------------------------------------------------------------------------

typedef __attribute__((ext_vector_type(8))) short short8;
typedef __attribute__((ext_vector_type(4))) float floatx4;

#define HID 128
#define NTY 4

__device__ __forceinline__ unsigned short f2bf(float f) {
    unsigned int u = __float_as_uint(f);
    unsigned int r = (u + 0x7fffu + ((u >> 16) & 1u)) >> 16;  // RNE
    return (unsigned short)r;
}
__device__ __forceinline__ float bf2f(unsigned int lo16) {
    return __uint_as_float(lo16 << 16);
}

// ---- prep kernels ---------------------------------------------------------

__global__ void cvt_h_kernel(const float* __restrict__ h, unsigned short* __restrict__ hbf, int total4) {
    int i = blockIdx.x * blockDim.x + threadIdx.x;
    if (i >= total4) return;
    float4 v = ((const float4*)h)[i];
    uint2 o;
    o.x = (unsigned int)f2bf(v.x) | ((unsigned int)f2bf(v.y) << 16);
    o.y = (unsigned int)f2bf(v.z) | ((unsigned int)f2bf(v.w) << 16);
    ((uint2*)hbf)[i] = o;
}

__global__ void pack_wmsg_kernel(const float* __restrict__ W, unsigned short* __restrict__ Wbf, int total) {
    int i = blockIdx.x * blockDim.x + threadIdx.x;
    if (i >= total) return;
    Wbf[i] = f2bf(W[i]);  // layout [t*128+i][k] already == [n][k]
}

// B'' [512][256]: see header comment
__global__ void pack_wgru_kernel(const float* __restrict__ w_ih, const float* __restrict__ w_hh,
                                 unsigned short* __restrict__ Wg) {
    int idx = blockIdx.x * blockDim.x + threadIdx.x;  // 512*256
    if (idx >= 512 * 256) return;
    int row = idx >> 8, k = idx & 255;
    int j = row >> 2, g = row & 3;
    float v = 0.0f;
    if (g == 0) v = (k < 128) ? w_ih[j * 128 + k]         : w_hh[j * 128 + (k - 128)];
    else if (g == 1) v = (k < 128) ? w_ih[(128 + j) * 128 + k] : w_hh[(128 + j) * 128 + (k - 128)];
    else if (g == 2) v = (k < 128) ? w_ih[(256 + j) * 128 + k] : 0.0f;
    else             v = (k < 128) ? 0.0f : w_hh[(256 + j) * 128 + (k - 128)];
    Wg[idx] = f2bf(v);
}

// ---- bf16 MFMA GEMM: C[M x 512] = A[M x K] @ B[512 x K]^T -----------------
// A split across two sources at column Asplit (for K=256 GRU case).
// Tile 128x128, BK=64, 4 waves in 2x2, each wave 64x64 via 4x4 of 16x16x32.

__global__ __launch_bounds__(256) void gemm_bf16(
    const unsigned short* __restrict__ A0, const unsigned short* __restrict__ A1,
    const unsigned short* __restrict__ B, unsigned short* __restrict__ C,
    int M, int K, int Asplit, int ldb) {
    __shared__ __align__(16) unsigned short As[128][72];  // +8 pad: 16B-aligned rows, conflict-free frags
    __shared__ __align__(16) unsigned short Bs[128][72];

    const int tid = threadIdx.x;
    const int m0 = blockIdx.x * 128;
    const int n0 = blockIdx.y * 128;
    const int lane = tid & 63, wave = tid >> 6;
    const int wm = wave >> 1, wn = wave & 1;
    const int lm = lane & 15, quad = lane >> 4;
    const int lrow = tid >> 3;        // 0..31
    const int lcol = (tid & 7) * 8;   // 0..56

    floatx4 acc[4][4];
#pragma unroll
    for (int a = 0; a < 4; ++a)
#pragma unroll
        for (int b = 0; b < 4; ++b) acc[a][b] = (floatx4){0.f, 0.f, 0.f, 0.f};

    for (int kc = 0; kc < K; kc += 64) {
        const unsigned short* Ap;
        int ko;
        if (kc < Asplit) { Ap = A0; ko = kc; } else { Ap = A1; ko = kc - Asplit; }
#pragma unroll
        for (int p = 0; p < 4; ++p) {
            int r = lrow + p * 32;
            int gm = m0 + r;
            uint4 v = {0u, 0u, 0u, 0u};
            if (gm < M) v = *(const uint4*)(Ap + (size_t)gm * HID + ko + lcol);
            *(uint4*)&As[r][lcol] = v;
            int gn = n0 + r;  // < 512 always
            uint4 w = *(const uint4*)(B + (size_t)gn * ldb + kc + lcol);
            *(uint4*)&Bs[r][lcol] = w;
        }
        __syncthreads();
#pragma unroll
        for (int s = 0; s < 2; ++s) {
            short8 af[4], bf[4];
#pragma unroll
            for (int mi = 0; mi < 4; ++mi)
                af[mi] = *(const short8*)&As[wm * 64 + mi * 16 + lm][s * 32 + quad * 8];
#pragma unroll
            for (int ni = 0; ni < 4; ++ni)
                bf[ni] = *(const short8*)&Bs[wn * 64 + ni * 16 + lm][s * 32 + quad * 8];
#pragma unroll
            for (int mi = 0; mi < 4; ++mi)
#pragma unroll
                for (int ni = 0; ni < 4; ++ni)
                    acc[mi][ni] = __builtin_amdgcn_mfma_f32_16x16x32_bf16(af[mi], bf[ni], acc[mi][ni], 0, 0, 0);
        }
        __syncthreads();
    }
    // C/D layout: col = lane&15, row = quad*4 + reg  [m89/m91]
#pragma unroll
    for (int mi = 0; mi < 4; ++mi) {
        int row_b = m0 + wm * 64 + mi * 16 + quad * 4;
#pragma unroll
        for (int ni = 0; ni < 4; ++ni) {
            int col = n0 + wn * 64 + ni * 16 + lm;
#pragma unroll
            for (int r = 0; r < 4; ++r) {
                int grow = row_b + r;
                if (grow < M) C[(size_t)grow * 512 + col] = f2bf(acc[mi][ni][r]);
            }
        }
    }
}

// ---- scatter: agg[dst] += Y[src, t, :]; cnt[dst,t] += 1 -------------------
// One wave per edge; lane handles 2 consecutive floats (one packed bf16x2).

__global__ void scatter_kernel(const int* __restrict__ src, const int* __restrict__ dst,
                               const int* __restrict__ ety, const unsigned short* __restrict__ Ybf,
                               float* __restrict__ agg, float* __restrict__ cnt, int E) {
    int wave = blockIdx.x * (blockDim.x >> 6) + (threadIdx.x >> 6);
    int lane = threadIdx.x & 63;
    int nw = gridDim.x * (blockDim.x >> 6);
    for (int e = wave; e < E; e += nw) {
        int s = src[e], d = dst[e], t = ety[e];
        unsigned int p = ((const unsigned int*)(Ybf + (size_t)s * 512 + t * HID))[lane];
        float f0 = bf2f(p & 0xffffu);
        float f1 = bf2f(p >> 16);
        float* arow = agg + (size_t)d * HID + lane * 2;
        atomicAdd(arow, f0);
        atomicAdd(arow + 1, f1);
        if (lane == 0) atomicAdd(cnt + d * NTY + t, 1.0f);
    }
}

// ---- aggb = agg + cnt @ edge_b, cast to bf16 ------------------------------

__global__ void cvt_agg_kernel(const float* __restrict__ agg, const float* __restrict__ cnt,
                               const float* __restrict__ eb, unsigned short* __restrict__ aggbf, int total) {
    int i = blockIdx.x * blockDim.x + threadIdx.x;
    if (i >= total) return;
    int n = i >> 7, j = i & 127;
    float v = agg[i];
    v += cnt[n * NTY + 0] * eb[0 * HID + j];
    v += cnt[n * NTY + 1] * eb[1 * HID + j];
    v += cnt[n * NTY + 2] * eb[2 * HID + j];
    v += cnt[n * NTY + 3] * eb[3 * HID + j];
    aggbf[i] = f2bf(v);
}

// ---- gates: read gate-interleaved G, apply GRU nonlinearity ----------------

__global__ void gates_kernel(const uint2* __restrict__ G, const float* __restrict__ h,
                             const float* __restrict__ b_ih, const float* __restrict__ b_hh,
                             float* __restrict__ out, int total) {
    int i = blockIdx.x * blockDim.x + threadIdx.x;
    if (i >= total) return;
    int j = i & 127;
    uint2 g = G[i];  // byte offset n*1024 + 8j == bf16 offset n*512 + 4j
    float g0 = bf2f(g.x & 0xffffu);
    float g1 = bf2f(g.x >> 16);
    float g2 = bf2f(g.y & 0xffffu);
    float g3 = bf2f(g.y >> 16);
    float r = 1.0f / (1.0f + __expf(-(g0 + b_ih[j] + b_hh[j])));
    float z = 1.0f / (1.0f + __expf(-(g1 + b_ih[128 + j] + b_hh[128 + j])));
    float nn = tanhf(g2 + b_ih[256 + j] + r * (g3 + b_hh[256 + j]));
    float hv = h[i];
    out[i] = (1.0f - z) * nn + z * hv;
}

// ---------------------------------------------------------------------------

extern "C" void kernel_launch(void* const* d_in, const int* in_sizes, int n_in,
                              void* d_out, int out_size, void* d_ws, size_t ws_size,
                              hipStream_t stream) {
    const float* node_states = (const float*)d_in[0];
    const int*   edge_index  = (const int*)d_in[1];  // [2,E] int32 per harness convention
    const int*   edge_type   = (const int*)d_in[2];
    const float* edge_W      = (const float*)d_in[3];
    const float* edge_b      = (const float*)d_in[4];
    const float* w_ih        = (const float*)d_in[5];
    const float* w_hh        = (const float*)d_in[6];
    const float* b_ih        = (const float*)d_in[7];
    const float* b_hh        = (const float*)d_in[8];

    const int M = in_sizes[0] / HID;      // 50000
    const int E = in_sizes[1] / 2;        // 625000
    const int* src = edge_index;
    const int* dst = edge_index + E;

    // workspace layout (bytes) -- total ~78 MB
    char* ws = (char*)d_ws;
    size_t off = 0;
    unsigned short* hbf   = (unsigned short*)(ws + off); off += (size_t)M * HID * 2;        // 12.8MB
    unsigned short* aggbf = (unsigned short*)(ws + off); off += (size_t)M * HID * 2;        // 12.8MB
    unsigned short* Ybf   = (unsigned short*)(ws + off); off += (size_t)M * 512 * 2;        // 51.2MB (also G)
    unsigned short* Wmsg  = (unsigned short*)(ws + off); off += (size_t)512 * HID * 2;      // 128KB
    unsigned short* Wgru  = (unsigned short*)(ws + off); off += (size_t)512 * 256 * 2;      // 256KB
    float*          cnt   = (float*)(ws + off);          off += (size_t)M * NTY * 4;        // 800KB
    float* agg = (float*)d_out;  // agg accumulates in d_out, overwritten by gates at the end

    hipMemsetAsync(agg, 0, (size_t)M * HID * 4, stream);
    hipMemsetAsync(cnt, 0, (size_t)M * NTY * 4, stream);

    int t4 = M * HID / 4;
    cvt_h_kernel<<<(t4 + 255) / 256, 256, 0, stream>>>(node_states, hbf, t4);
    pack_wmsg_kernel<<<(512 * HID + 255) / 256, 256, 0, stream>>>(edge_W, Wmsg, 512 * HID);
    pack_wgru_kernel<<<(512 * 256 + 255) / 256, 256, 0, stream>>>(w_ih, w_hh, Wgru);

    dim3 ggrid((M + 127) / 128, 4);
    // Y = hbf @ Wmsg^T   (K=128)
    gemm_bf16<<<ggrid, 256, 0, stream>>>(hbf, hbf, Wmsg, Ybf, M, 128, 128, 128);

    scatter_kernel<<<1024, 256, 0, stream>>>(src, dst, edge_type, Ybf, agg, cnt, E);

    int tot = M * HID;
    cvt_agg_kernel<<<(tot + 255) / 256, 256, 0, stream>>>(agg, cnt, edge_b, aggbf, tot);

    // G = [aggbf|hbf] @ Wgru^T  (K=256), reuses Ybf buffer as G
    gemm_bf16<<<ggrid, 256, 0, stream>>>(aggbf, hbf, Wgru, Ybf, M, 256, 128, 256);

    gates_kernel<<<(tot + 255) / 256, 256, 0, stream>>>((const uint2*)Ybf, node_states, b_ih, b_hh,
                                                        (float*)d_out, tot);
}

// Round 2
// 331.249 us; speedup vs baseline: 2.2538x; 2.2538x over previous
//
#include <hip/hip_runtime.h>

// ---------------------------------------------------------------------------
// GGNN message passing, MI355X/gfx950.  Round 2: CSR gather-reduce replaces
// the fp32 atomic scatter (556us -> target ~100us).
//
// Math refactor (unchanged from R1):
//   Y[n,t,:] = W_t @ h[n]  via ONE GEMM [50000,128]@[128,512]
//   agg[n]   = sum_{e: dst=n} Y[src_e, t_e, :] + sum_t cnt[n,t]*b_t
//   GRU as single K=256 GEMM with gate-interleaved packed B.
//
// R2: build CSR on device (hist -> 3-phase exclusive scan -> fill with
// int atomics), then gather-reduce one wave per node: lane owns 2 columns,
// one coalesced 4B load per edge per lane, fp32 register accumulation,
// fused bias + bf16 convert.  625K*2 int atomics vs R1's 80M fp32 atomics.
// ---------------------------------------------------------------------------

typedef __attribute__((ext_vector_type(8))) short short8;
typedef __attribute__((ext_vector_type(4))) float floatx4;

#define HID 128
#define NTY 4

__device__ __forceinline__ unsigned short f2bf(float f) {
    unsigned int u = __float_as_uint(f);
    unsigned int r = (u + 0x7fffu + ((u >> 16) & 1u)) >> 16;  // RNE
    return (unsigned short)r;
}
__device__ __forceinline__ float bf2f(unsigned int lo16) {
    return __uint_as_float(lo16 << 16);
}

// ---- prep kernels ---------------------------------------------------------

__global__ void cvt_h_kernel(const float* __restrict__ h, unsigned short* __restrict__ hbf, int total4) {
    int i = blockIdx.x * blockDim.x + threadIdx.x;
    if (i >= total4) return;
    float4 v = ((const float4*)h)[i];
    uint2 o;
    o.x = (unsigned int)f2bf(v.x) | ((unsigned int)f2bf(v.y) << 16);
    o.y = (unsigned int)f2bf(v.z) | ((unsigned int)f2bf(v.w) << 16);
    ((uint2*)hbf)[i] = o;
}

__global__ void pack_wmsg_kernel(const float* __restrict__ W, unsigned short* __restrict__ Wbf, int total) {
    int i = blockIdx.x * blockDim.x + threadIdx.x;
    if (i >= total) return;
    Wbf[i] = f2bf(W[i]);  // layout [t*128+i][k] already == [n][k]
}

// B'' [512][256]: rows 4j+{0,1,2,3} = r|z|i_n|h_n for out col j (see header)
__global__ void pack_wgru_kernel(const float* __restrict__ w_ih, const float* __restrict__ w_hh,
                                 unsigned short* __restrict__ Wg) {
    int idx = blockIdx.x * blockDim.x + threadIdx.x;  // 512*256
    if (idx >= 512 * 256) return;
    int row = idx >> 8, k = idx & 255;
    int j = row >> 2, g = row & 3;
    float v = 0.0f;
    if (g == 0) v = (k < 128) ? w_ih[j * 128 + k]         : w_hh[j * 128 + (k - 128)];
    else if (g == 1) v = (k < 128) ? w_ih[(128 + j) * 128 + k] : w_hh[(128 + j) * 128 + (k - 128)];
    else if (g == 2) v = (k < 128) ? w_ih[(256 + j) * 128 + k] : 0.0f;
    else             v = (k < 128) ? 0.0f : w_hh[(256 + j) * 128 + (k - 128)];
    Wg[idx] = f2bf(v);
}

// ---- bf16 MFMA GEMM: C[M x 512] = A[M x K] @ B[512 x K]^T -----------------
// A split across two sources at column Asplit (for K=256 GRU case).
// Tile 128x128, BK=64, 4 waves in 2x2, each wave 64x64 via 4x4 of 16x16x32.

__global__ __launch_bounds__(256) void gemm_bf16(
    const unsigned short* __restrict__ A0, const unsigned short* __restrict__ A1,
    const unsigned short* __restrict__ B, unsigned short* __restrict__ C,
    int M, int K, int Asplit, int ldb) {
    __shared__ __align__(16) unsigned short As[128][72];
    __shared__ __align__(16) unsigned short Bs[128][72];

    const int tid = threadIdx.x;
    const int m0 = blockIdx.x * 128;
    const int n0 = blockIdx.y * 128;
    const int lane = tid & 63, wave = tid >> 6;
    const int wm = wave >> 1, wn = wave & 1;
    const int lm = lane & 15, quad = lane >> 4;
    const int lrow = tid >> 3;        // 0..31
    const int lcol = (tid & 7) * 8;   // 0..56

    floatx4 acc[4][4];
#pragma unroll
    for (int a = 0; a < 4; ++a)
#pragma unroll
        for (int b = 0; b < 4; ++b) acc[a][b] = (floatx4){0.f, 0.f, 0.f, 0.f};

    for (int kc = 0; kc < K; kc += 64) {
        const unsigned short* Ap;
        int ko;
        if (kc < Asplit) { Ap = A0; ko = kc; } else { Ap = A1; ko = kc - Asplit; }
#pragma unroll
        for (int p = 0; p < 4; ++p) {
            int r = lrow + p * 32;
            int gm = m0 + r;
            uint4 v = {0u, 0u, 0u, 0u};
            if (gm < M) v = *(const uint4*)(Ap + (size_t)gm * HID + ko + lcol);
            *(uint4*)&As[r][lcol] = v;
            int gn = n0 + r;  // < 512 always
            uint4 w = *(const uint4*)(B + (size_t)gn * ldb + kc + lcol);
            *(uint4*)&Bs[r][lcol] = w;
        }
        __syncthreads();
#pragma unroll
        for (int s = 0; s < 2; ++s) {
            short8 af[4], bfr[4];
#pragma unroll
            for (int mi = 0; mi < 4; ++mi)
                af[mi] = *(const short8*)&As[wm * 64 + mi * 16 + lm][s * 32 + quad * 8];
#pragma unroll
            for (int ni = 0; ni < 4; ++ni)
                bfr[ni] = *(const short8*)&Bs[wn * 64 + ni * 16 + lm][s * 32 + quad * 8];
#pragma unroll
            for (int mi = 0; mi < 4; ++mi)
#pragma unroll
                for (int ni = 0; ni < 4; ++ni)
                    acc[mi][ni] = __builtin_amdgcn_mfma_f32_16x16x32_bf16(af[mi], bfr[ni], acc[mi][ni], 0, 0, 0);
        }
        __syncthreads();
    }
    // C/D layout: col = lane&15, row = quad*4 + reg  [m89/m91]
#pragma unroll
    for (int mi = 0; mi < 4; ++mi) {
        int row_b = m0 + wm * 64 + mi * 16 + quad * 4;
#pragma unroll
        for (int ni = 0; ni < 4; ++ni) {
            int col = n0 + wn * 64 + ni * 16 + lm;
#pragma unroll
            for (int r = 0; r < 4; ++r) {
                int grow = row_b + r;
                if (grow < M) C[(size_t)grow * 512 + col] = f2bf(acc[mi][ni][r]);
            }
        }
    }
}

// ---- CSR construction -----------------------------------------------------

__global__ void hist_kernel(const int* __restrict__ dst, int* __restrict__ deg, int E) {
    int e = blockIdx.x * blockDim.x + threadIdx.x;
    if (e < E) atomicAdd(&deg[dst[e]], 1);
}

// per-block exclusive scan of deg (256 elems/block); partial -> rowptr, total -> blocksum
__global__ void scan_blocks_kernel(const int* __restrict__ deg, int* __restrict__ rowptr,
                                   int* __restrict__ blocksum, int N) {
    __shared__ int s[256];
    int t = threadIdx.x;
    int i = blockIdx.x * 256 + t;
    int v = (i < N) ? deg[i] : 0;
    s[t] = v;
    __syncthreads();
#pragma unroll
    for (int off = 1; off < 256; off <<= 1) {
        int x = (t >= off) ? s[t - off] : 0;
        __syncthreads();
        s[t] += x;
        __syncthreads();
    }
    if (i < N) rowptr[i] = s[t] - v;  // exclusive
    if (t == 255) blocksum[blockIdx.x] = s[t];
}

// single-block scan of <=256 block sums -> exclusive blockoff
__global__ void scan_top_kernel(const int* __restrict__ blocksum, int* __restrict__ blockoff, int nb) {
    __shared__ int s[256];
    int t = threadIdx.x;
    int v = (t < nb) ? blocksum[t] : 0;
    s[t] = v;
    __syncthreads();
#pragma unroll
    for (int off = 1; off < 256; off <<= 1) {
        int x = (t >= off) ? s[t - off] : 0;
        __syncthreads();
        s[t] += x;
        __syncthreads();
    }
    if (t < nb) blockoff[t] = s[t] - v;
}

__global__ void finalize_kernel(int* __restrict__ rowptr, const int* __restrict__ blockoff,
                                int* __restrict__ cursor, int N) {
    int i = blockIdx.x * blockDim.x + threadIdx.x;
    if (i >= N) return;
    int r = rowptr[i] + blockoff[i >> 8];
    rowptr[i] = r;
    cursor[i] = r;
}

__global__ void fill_kernel(const int* __restrict__ src, const int* __restrict__ dst,
                            const int* __restrict__ ety, int* __restrict__ cursor,
                            int* __restrict__ csr, int E) {
    int e = blockIdx.x * blockDim.x + threadIdx.x;
    if (e >= E) return;
    int pos = atomicAdd(&cursor[dst[e]], 1);
    csr[pos] = (src[e] << 2) | ety[e];
}

// ---- gather-reduce: one wave per node; lane owns cols {2l, 2l+1} ----------
// agg[n] = sum_e Y[src_e, t_e, :] + sum_t cnt_t * b_t, write bf16 aggbf.

__global__ void gather_kernel(const int* __restrict__ rowptr, const int* __restrict__ deg,
                              const int* __restrict__ csr, const unsigned short* __restrict__ Ybf,
                              const float* __restrict__ eb, unsigned short* __restrict__ aggbf, int N) {
    int w = blockIdx.x * (blockDim.x >> 6) + (threadIdx.x >> 6);
    if (w >= N) return;
    int lane = threadIdx.x & 63;
    int start = rowptr[w];
    int end = start + deg[w];
    float a0 = 0.f, a1 = 0.f;
    int c0 = 0, c1 = 0, c2 = 0, c3 = 0;
    for (int e = start; e < end; ++e) {
        int pk = csr[e];  // same addr across lanes -> broadcast
        int t = pk & 3;
        int s = pk >> 2;
        unsigned int p = ((const unsigned int*)(Ybf + (size_t)s * 512 + t * HID))[lane];
        a0 += bf2f(p & 0xffffu);
        a1 += bf2f(p >> 16);
        c0 += (t == 0); c1 += (t == 1); c2 += (t == 2); c3 += (t == 3);
    }
    int col = lane * 2;
    a0 += c0 * eb[col]     + c1 * eb[HID + col]     + c2 * eb[2 * HID + col]     + c3 * eb[3 * HID + col];
    a1 += c0 * eb[col + 1] + c1 * eb[HID + col + 1] + c2 * eb[2 * HID + col + 1] + c3 * eb[3 * HID + col + 1];
    unsigned int o = (unsigned int)f2bf(a0) | ((unsigned int)f2bf(a1) << 16);
    ((unsigned int*)(aggbf + (size_t)w * HID))[lane] = o;
}

// ---- gates: read gate-interleaved G, apply GRU nonlinearity ----------------

__global__ void gates_kernel(const uint2* __restrict__ G, const float* __restrict__ h,
                             const float* __restrict__ b_ih, const float* __restrict__ b_hh,
                             float* __restrict__ out, int total) {
    int i = blockIdx.x * blockDim.x + threadIdx.x;
    if (i >= total) return;
    int j = i & 127;
    uint2 g = G[i];  // bf16 offset n*512 + 4j
    float g0 = bf2f(g.x & 0xffffu);
    float g1 = bf2f(g.x >> 16);
    float g2 = bf2f(g.y & 0xffffu);
    float g3 = bf2f(g.y >> 16);
    float r = 1.0f / (1.0f + __expf(-(g0 + b_ih[j] + b_hh[j])));
    float z = 1.0f / (1.0f + __expf(-(g1 + b_ih[128 + j] + b_hh[128 + j])));
    float nn = tanhf(g2 + b_ih[256 + j] + r * (g3 + b_hh[256 + j]));
    float hv = h[i];
    out[i] = (1.0f - z) * nn + z * hv;
}

// ---------------------------------------------------------------------------

extern "C" void kernel_launch(void* const* d_in, const int* in_sizes, int n_in,
                              void* d_out, int out_size, void* d_ws, size_t ws_size,
                              hipStream_t stream) {
    const float* node_states = (const float*)d_in[0];
    const int*   edge_index  = (const int*)d_in[1];
    const int*   edge_type   = (const int*)d_in[2];
    const float* edge_W      = (const float*)d_in[3];
    const float* edge_b      = (const float*)d_in[4];
    const float* w_ih        = (const float*)d_in[5];
    const float* w_hh        = (const float*)d_in[6];
    const float* b_ih        = (const float*)d_in[7];
    const float* b_hh        = (const float*)d_in[8];

    const int M = in_sizes[0] / HID;      // 50000 nodes
    const int E = in_sizes[1] / 2;        // 625000 edges
    const int* src = edge_index;
    const int* dst = edge_index + E;

    // workspace layout
    char* ws = (char*)d_ws;
    size_t off = 0;
    unsigned short* hbf   = (unsigned short*)(ws + off); off += (size_t)M * HID * 2;    // 12.8MB
    unsigned short* aggbf = (unsigned short*)(ws + off); off += (size_t)M * HID * 2;    // 12.8MB
    unsigned short* Ybf   = (unsigned short*)(ws + off); off += (size_t)M * 512 * 2;    // 51.2MB (also G)
    unsigned short* Wmsg  = (unsigned short*)(ws + off); off += (size_t)512 * HID * 2;  // 128KB
    unsigned short* Wgru  = (unsigned short*)(ws + off); off += (size_t)512 * 256 * 2;  // 256KB
    int* deg      = (int*)(ws + off); off += (size_t)M * 4;        // 200KB
    int* rowptr   = (int*)(ws + off); off += (size_t)M * 4;        // 200KB
    int* cursor   = (int*)(ws + off); off += (size_t)M * 4;        // 200KB
    int* blocksum = (int*)(ws + off); off += 256 * 4;
    int* blockoff = (int*)(ws + off); off += 256 * 4;
    int* csr      = (int*)(ws + off); off += (size_t)E * 4;        // 2.5MB

    const int nb = (M + 255) / 256;  // 196 <= 256

    hipMemsetAsync(deg, 0, (size_t)M * 4, stream);

    int t4 = M * HID / 4;
    cvt_h_kernel<<<(t4 + 255) / 256, 256, 0, stream>>>(node_states, hbf, t4);
    pack_wmsg_kernel<<<(512 * HID + 255) / 256, 256, 0, stream>>>(edge_W, Wmsg, 512 * HID);
    pack_wgru_kernel<<<(512 * 256 + 255) / 256, 256, 0, stream>>>(w_ih, w_hh, Wgru);

    // CSR build (overlaps conceptually with GEMM but stream-ordered; all cheap)
    hist_kernel<<<(E + 255) / 256, 256, 0, stream>>>(dst, deg, E);
    scan_blocks_kernel<<<nb, 256, 0, stream>>>(deg, rowptr, blocksum, M);
    scan_top_kernel<<<1, 256, 0, stream>>>(blocksum, blockoff, nb);
    finalize_kernel<<<(M + 255) / 256, 256, 0, stream>>>(rowptr, blockoff, cursor, M);
    fill_kernel<<<(E + 255) / 256, 256, 0, stream>>>(src, dst, edge_type, cursor, csr, E);

    dim3 ggrid((M + 127) / 128, 4);
    // Y = hbf @ Wmsg^T   (K=128)
    gemm_bf16<<<ggrid, 256, 0, stream>>>(hbf, hbf, Wmsg, Ybf, M, 128, 128, 128);

    // agg gather-reduce + bias, straight to bf16
    gather_kernel<<<(M + 3) / 4, 256, 0, stream>>>(rowptr, deg, csr, Ybf, edge_b, aggbf, M);

    // G = [aggbf|hbf] @ Wgru^T  (K=256), reuses Ybf buffer as G
    gemm_bf16<<<ggrid, 256, 0, stream>>>(aggbf, hbf, Wgru, Ybf, M, 256, 128, 256);

    int tot = M * HID;
    gates_kernel<<<(tot + 255) / 256, 256, 0, stream>>>((const uint2*)Ybf, node_states, b_ih, b_hh,
                                                        (float*)d_out, tot);
}

// Round 3
// 316.237 us; speedup vs baseline: 2.3607x; 1.0475x over previous
//
#include <hip/hip_runtime.h>

// ---------------------------------------------------------------------------
// GGNN message passing, MI355X/gfx950.  Round 3:
//   - gather: 4x unrolled edge loop (4 independent loads in flight) + packed
//     type counters.  R2 was latency-bound (VALUBusy 32%, HBM 15%, VGPR=12).
//   - gemm_y: BK=128 single-stage, B (Wmsg, 128KB L2-hot) loaded direct to
//     registers, only A through LDS, one barrier round.
//   - gemm_gru: operand-swapped C' = Wgru @ X^T so one lane's 4 acc regs =
//     the 4 gate pre-acts (r,z,i_n,h_n) of one (node,j); GRU nonlinearity
//     fused into the epilogue, writes out directly.  Kills G round-trip
//     (102MB traffic) + gates kernel.
//
// Math refactor (unchanged):
//   Y[n,t,:] = W_t @ h[n]  via ONE GEMM [50000,128]@[128,512]
//   agg[n]   = sum_{e: dst=n} Y[src_e, t_e, :] + sum_t cnt[n,t]*b_t
//   GRU via packed B'' rows 4j+{0..3} = r|z|i_n|h_n over K=256 = [aggb|h].
// ---------------------------------------------------------------------------

typedef __attribute__((ext_vector_type(8))) short short8;
typedef __attribute__((ext_vector_type(4))) float floatx4;

#define HID 128
#define NTY 4

__device__ __forceinline__ unsigned short f2bf(float f) {
    unsigned int u = __float_as_uint(f);
    unsigned int r = (u + 0x7fffu + ((u >> 16) & 1u)) >> 16;  // RNE
    return (unsigned short)r;
}
__device__ __forceinline__ float bf2f(unsigned int lo16) {
    return __uint_as_float(lo16 << 16);
}

// ---- prep kernels ---------------------------------------------------------

__global__ void cvt_h_kernel(const float* __restrict__ h, unsigned short* __restrict__ hbf, int total4) {
    int i = blockIdx.x * blockDim.x + threadIdx.x;
    if (i >= total4) return;
    float4 v = ((const float4*)h)[i];
    uint2 o;
    o.x = (unsigned int)f2bf(v.x) | ((unsigned int)f2bf(v.y) << 16);
    o.y = (unsigned int)f2bf(v.z) | ((unsigned int)f2bf(v.w) << 16);
    ((uint2*)hbf)[i] = o;
}

__global__ void pack_wmsg_kernel(const float* __restrict__ W, unsigned short* __restrict__ Wbf, int total) {
    int i = blockIdx.x * blockDim.x + threadIdx.x;
    if (i >= total) return;
    Wbf[i] = f2bf(W[i]);  // [t*128+i][k] already == [n][k]
}

// B'' [512][256]: rows 4j+{0,1,2,3} = r|z|i_n|h_n for out col j
__global__ void pack_wgru_kernel(const float* __restrict__ w_ih, const float* __restrict__ w_hh,
                                 unsigned short* __restrict__ Wg) {
    int idx = blockIdx.x * blockDim.x + threadIdx.x;  // 512*256
    if (idx >= 512 * 256) return;
    int row = idx >> 8, k = idx & 255;
    int j = row >> 2, g = row & 3;
    float v = 0.0f;
    if (g == 0) v = (k < 128) ? w_ih[j * 128 + k]         : w_hh[j * 128 + (k - 128)];
    else if (g == 1) v = (k < 128) ? w_ih[(128 + j) * 128 + k] : w_hh[(128 + j) * 128 + (k - 128)];
    else if (g == 2) v = (k < 128) ? w_ih[(256 + j) * 128 + k] : 0.0f;
    else             v = (k < 128) ? 0.0f : w_hh[(256 + j) * 128 + (k - 128)];
    Wg[idx] = f2bf(v);
}

// ---- GEMM-Y: C[M x 512] = A[M x 128] @ B[512 x 128]^T, BK=K=128 -----------
// B direct to registers (128KB, L2-hot); A staged once through LDS.

__global__ __launch_bounds__(256) void gemm_y(const unsigned short* __restrict__ A,
                                              const unsigned short* __restrict__ Bw,
                                              unsigned short* __restrict__ C, int M) {
    __shared__ __align__(16) unsigned short As[128][136];
    const int tid = threadIdx.x;
    const int m0 = blockIdx.x * 128, n0 = blockIdx.y * 128;
    const int lane = tid & 63, wave = tid >> 6;
    const int wm = wave >> 1, wn = wave & 1;
    const int lm = lane & 15, quad = lane >> 4;

    // stage A tile (coalesced uint4)
    {
        int rr = tid >> 4;         // 0..15
        int cc = (tid & 15) * 8;   // 0..120 (shorts)
#pragma unroll
        for (int p = 0; p < 8; ++p) {
            int r = rr + p * 16;
            int gm = m0 + r;
            uint4 v = {0u, 0u, 0u, 0u};
            if (gm < M) v = *(const uint4*)(A + (size_t)gm * HID + cc);
            *(uint4*)&As[r][cc] = v;
        }
    }
    // B fragments direct from global
    short8 bfrag[4][4];
#pragma unroll
    for (int ni = 0; ni < 4; ++ni) {
        int n = n0 + wn * 64 + ni * 16 + lm;
#pragma unroll
        for (int s = 0; s < 4; ++s)
            bfrag[ni][s] = *(const short8*)(Bw + (size_t)n * HID + s * 32 + quad * 8);
    }
    floatx4 acc[4][4];
#pragma unroll
    for (int a = 0; a < 4; ++a)
#pragma unroll
        for (int b = 0; b < 4; ++b) acc[a][b] = (floatx4){0.f, 0.f, 0.f, 0.f};

    __syncthreads();
#pragma unroll
    for (int s = 0; s < 4; ++s) {
        short8 af[4];
#pragma unroll
        for (int mi = 0; mi < 4; ++mi)
            af[mi] = *(const short8*)&As[wm * 64 + mi * 16 + lm][s * 32 + quad * 8];
#pragma unroll
        for (int mi = 0; mi < 4; ++mi)
#pragma unroll
            for (int ni = 0; ni < 4; ++ni)
                acc[mi][ni] = __builtin_amdgcn_mfma_f32_16x16x32_bf16(af[mi], bfrag[ni][s], acc[mi][ni], 0, 0, 0);
    }
    // C/D: col = lane&15, row = quad*4 + reg
#pragma unroll
    for (int mi = 0; mi < 4; ++mi) {
        int row_b = m0 + wm * 64 + mi * 16 + quad * 4;
#pragma unroll
        for (int ni = 0; ni < 4; ++ni) {
            int col = n0 + wn * 64 + ni * 16 + lm;
#pragma unroll
            for (int r = 0; r < 4; ++r) {
                int grow = row_b + r;
                if (grow < M) C[(size_t)grow * 512 + col] = f2bf(acc[mi][ni][r]);
            }
        }
    }
}

// ---- GEMM-GRU fused: C'[512 x M] = Wg[512x256] @ X[Mx256]^T ---------------
// X rows = [aggbf | hbf].  acc row dim = gate rows (4j+g), col dim = nodes.
// One lane's acc[mi][ni][0..3] = (r,z,i_n,h_n) pre-acts of (node, j) ->
// apply GRU nonlinearity in epilogue, write out[node][j] directly.

__global__ __launch_bounds__(256) void gemm_gru(const unsigned short* __restrict__ Wg,
                                                const unsigned short* __restrict__ aggbf,
                                                const unsigned short* __restrict__ hbf,
                                                const float* __restrict__ h,
                                                const float* __restrict__ b_ih,
                                                const float* __restrict__ b_hh,
                                                float* __restrict__ out, int M) {
    __shared__ __align__(16) unsigned short Xs[128][136];
    const int tid = threadIdx.x;
    const int n0 = blockIdx.x * 128;  // node tile
    const int m0 = blockIdx.y * 128;  // gate-row tile (0,128,256,384)
    const int lane = tid & 63, wave = tid >> 6;
    const int wm = wave >> 1, wn = wave & 1;
    const int lm = lane & 15, quad = lane >> 4;

    floatx4 acc[4][4];
#pragma unroll
    for (int a = 0; a < 4; ++a)
#pragma unroll
        for (int b = 0; b < 4; ++b) acc[a][b] = (floatx4){0.f, 0.f, 0.f, 0.f};

    for (int c = 0; c < 2; ++c) {
        const unsigned short* Xp = c ? hbf : aggbf;
        // stage X tile (rows = nodes, cols = 128 k of this chunk)
        {
            int rr = tid >> 4;
            int cc = (tid & 15) * 8;
#pragma unroll
            for (int p = 0; p < 8; ++p) {
                int r = rr + p * 16;
                int gn = n0 + r;
                uint4 v = {0u, 0u, 0u, 0u};
                if (gn < M) v = *(const uint4*)(Xp + (size_t)gn * HID + cc);
                *(uint4*)&Xs[r][cc] = v;
            }
        }
        // A (Wg) fragments direct from global (256KB, L2-hot)
        short8 afrag[4][4];
#pragma unroll
        for (int mi = 0; mi < 4; ++mi) {
            int rowg = m0 + wm * 64 + mi * 16 + lm;
#pragma unroll
            for (int s = 0; s < 4; ++s)
                afrag[mi][s] = *(const short8*)(Wg + (size_t)rowg * 256 + c * 128 + s * 32 + quad * 8);
        }
        __syncthreads();
#pragma unroll
        for (int s = 0; s < 4; ++s) {
            short8 bf[4];
#pragma unroll
            for (int ni = 0; ni < 4; ++ni)
                bf[ni] = *(const short8*)&Xs[wn * 64 + ni * 16 + lm][s * 32 + quad * 8];
#pragma unroll
            for (int mi = 0; mi < 4; ++mi)
#pragma unroll
                for (int ni = 0; ni < 4; ++ni)
                    acc[mi][ni] = __builtin_amdgcn_mfma_f32_16x16x32_bf16(afrag[mi][s], bf[ni], acc[mi][ni], 0, 0, 0);
        }
        __syncthreads();  // protect Xs restage
    }

    // epilogue: row = m0 + wm*64 + mi*16 + quad*4 + r  ->  j = row>>2, g = r
#pragma unroll
    for (int mi = 0; mi < 4; ++mi) {
        int j = (m0 >> 2) + wm * 16 + mi * 4 + quad;  // 0..127
        float brj = b_ih[j] + b_hh[j];
        float bzj = b_ih[128 + j] + b_hh[128 + j];
        float bin = b_ih[256 + j];
        float bhn = b_hh[256 + j];
#pragma unroll
        for (int ni = 0; ni < 4; ++ni) {
            int node = n0 + wn * 64 + ni * 16 + lm;
            if (node < M) {
                float g0 = acc[mi][ni][0], g1 = acc[mi][ni][1];
                float g2 = acc[mi][ni][2], g3 = acc[mi][ni][3];
                float r = 1.0f / (1.0f + __expf(-(g0 + brj)));
                float z = 1.0f / (1.0f + __expf(-(g1 + bzj)));
                float nn = tanhf(g2 + bin + r * (g3 + bhn));
                float hv = h[(size_t)node * HID + j];
                out[(size_t)node * HID + j] = (1.0f - z) * nn + z * hv;
            }
        }
    }
}

// ---- CSR construction -----------------------------------------------------

__global__ void hist_kernel(const int* __restrict__ dst, int* __restrict__ deg, int E) {
    int e = blockIdx.x * blockDim.x + threadIdx.x;
    if (e < E) atomicAdd(&deg[dst[e]], 1);
}

__global__ void scan_blocks_kernel(const int* __restrict__ deg, int* __restrict__ rowptr,
                                   int* __restrict__ blocksum, int N) {
    __shared__ int s[256];
    int t = threadIdx.x;
    int i = blockIdx.x * 256 + t;
    int v = (i < N) ? deg[i] : 0;
    s[t] = v;
    __syncthreads();
#pragma unroll
    for (int off = 1; off < 256; off <<= 1) {
        int x = (t >= off) ? s[t - off] : 0;
        __syncthreads();
        s[t] += x;
        __syncthreads();
    }
    if (i < N) rowptr[i] = s[t] - v;  // exclusive
    if (t == 255) blocksum[blockIdx.x] = s[t];
}

__global__ void scan_top_kernel(const int* __restrict__ blocksum, int* __restrict__ blockoff, int nb) {
    __shared__ int s[256];
    int t = threadIdx.x;
    int v = (t < nb) ? blocksum[t] : 0;
    s[t] = v;
    __syncthreads();
#pragma unroll
    for (int off = 1; off < 256; off <<= 1) {
        int x = (t >= off) ? s[t - off] : 0;
        __syncthreads();
        s[t] += x;
        __syncthreads();
    }
    if (t < nb) blockoff[t] = s[t] - v;
}

__global__ void finalize_kernel(int* __restrict__ rowptr, const int* __restrict__ blockoff,
                                int* __restrict__ cursor, int N) {
    int i = blockIdx.x * blockDim.x + threadIdx.x;
    if (i >= N) return;
    int r = rowptr[i] + blockoff[i >> 8];
    rowptr[i] = r;
    cursor[i] = r;
}

__global__ void fill_kernel(const int* __restrict__ src, const int* __restrict__ dst,
                            const int* __restrict__ ety, int* __restrict__ cursor,
                            int* __restrict__ csr, int E) {
    int e = blockIdx.x * blockDim.x + threadIdx.x;
    if (e >= E) return;
    int pos = atomicAdd(&cursor[dst[e]], 1);
    csr[pos] = (src[e] << 2) | ety[e];
}

// ---- gather-reduce: one wave per node, 4x unrolled for MLP ----------------

__global__ void gather_kernel(const int* __restrict__ rowptr, const int* __restrict__ deg,
                              const int* __restrict__ csr, const unsigned short* __restrict__ Ybf,
                              const float* __restrict__ eb, unsigned short* __restrict__ aggbf, int N) {
    int w = blockIdx.x * (blockDim.x >> 6) + (threadIdx.x >> 6);
    if (w >= N) return;
    int lane = threadIdx.x & 63;
    int start = rowptr[w];
    int end = start + deg[w];
    const unsigned int* Yu = (const unsigned int*)Ybf;  // uint idx: n*256 + t*64 + lane
    float a0 = 0.f, a1 = 0.f;
    unsigned int cpack = 0;  // per-type counts in 4 bytes (deg << 255 per type)
    int e = start;
    for (; e + 4 <= end; e += 4) {
        int p0 = csr[e], p1 = csr[e + 1], p2 = csr[e + 2], p3 = csr[e + 3];
        unsigned int u0 = Yu[(size_t)(p0 >> 2) * 256 + (p0 & 3) * 64 + lane];
        unsigned int u1 = Yu[(size_t)(p1 >> 2) * 256 + (p1 & 3) * 64 + lane];
        unsigned int u2 = Yu[(size_t)(p2 >> 2) * 256 + (p2 & 3) * 64 + lane];
        unsigned int u3 = Yu[(size_t)(p3 >> 2) * 256 + (p3 & 3) * 64 + lane];
        cpack += (1u << ((p0 & 3) << 3)) + (1u << ((p1 & 3) << 3))
               + (1u << ((p2 & 3) << 3)) + (1u << ((p3 & 3) << 3));
        a0 += bf2f(u0 & 0xffffu) + bf2f(u1 & 0xffffu) + bf2f(u2 & 0xffffu) + bf2f(u3 & 0xffffu);
        a1 += bf2f(u0 >> 16) + bf2f(u1 >> 16) + bf2f(u2 >> 16) + bf2f(u3 >> 16);
    }
    for (; e < end; ++e) {
        int pk = csr[e];
        unsigned int p = Yu[(size_t)(pk >> 2) * 256 + (pk & 3) * 64 + lane];
        cpack += 1u << ((pk & 3) << 3);
        a0 += bf2f(p & 0xffffu);
        a1 += bf2f(p >> 16);
    }
    float c0 = (float)(cpack & 255u), c1 = (float)((cpack >> 8) & 255u);
    float c2 = (float)((cpack >> 16) & 255u), c3 = (float)(cpack >> 24);
    int col = lane * 2;
    a0 += c0 * eb[col]     + c1 * eb[HID + col]     + c2 * eb[2 * HID + col]     + c3 * eb[3 * HID + col];
    a1 += c0 * eb[col + 1] + c1 * eb[HID + col + 1] + c2 * eb[2 * HID + col + 1] + c3 * eb[3 * HID + col + 1];
    unsigned int o = (unsigned int)f2bf(a0) | ((unsigned int)f2bf(a1) << 16);
    ((unsigned int*)(aggbf + (size_t)w * HID))[lane] = o;
}

// ---------------------------------------------------------------------------

extern "C" void kernel_launch(void* const* d_in, const int* in_sizes, int n_in,
                              void* d_out, int out_size, void* d_ws, size_t ws_size,
                              hipStream_t stream) {
    const float* node_states = (const float*)d_in[0];
    const int*   edge_index  = (const int*)d_in[1];
    const int*   edge_type   = (const int*)d_in[2];
    const float* edge_W      = (const float*)d_in[3];
    const float* edge_b      = (const float*)d_in[4];
    const float* w_ih        = (const float*)d_in[5];
    const float* w_hh        = (const float*)d_in[6];
    const float* b_ih        = (const float*)d_in[7];
    const float* b_hh        = (const float*)d_in[8];

    const int M = in_sizes[0] / HID;      // 50000 nodes
    const int E = in_sizes[1] / 2;        // 625000 edges
    const int* src = edge_index;
    const int* dst = edge_index + E;

    // workspace layout
    char* ws = (char*)d_ws;
    size_t off = 0;
    unsigned short* hbf   = (unsigned short*)(ws + off); off += (size_t)M * HID * 2;    // 12.8MB
    unsigned short* aggbf = (unsigned short*)(ws + off); off += (size_t)M * HID * 2;    // 12.8MB
    unsigned short* Ybf   = (unsigned short*)(ws + off); off += (size_t)M * 512 * 2;    // 51.2MB
    unsigned short* Wmsg  = (unsigned short*)(ws + off); off += (size_t)512 * HID * 2;  // 128KB
    unsigned short* Wgru  = (unsigned short*)(ws + off); off += (size_t)512 * 256 * 2;  // 256KB
    int* deg      = (int*)(ws + off); off += (size_t)M * 4;
    int* rowptr   = (int*)(ws + off); off += (size_t)M * 4;
    int* cursor   = (int*)(ws + off); off += (size_t)M * 4;
    int* blocksum = (int*)(ws + off); off += 256 * 4;
    int* blockoff = (int*)(ws + off); off += 256 * 4;
    int* csr      = (int*)(ws + off); off += (size_t)E * 4;

    const int nb = (M + 255) / 256;  // 196 <= 256

    hipMemsetAsync(deg, 0, (size_t)M * 4, stream);

    int t4 = M * HID / 4;
    cvt_h_kernel<<<(t4 + 255) / 256, 256, 0, stream>>>(node_states, hbf, t4);
    pack_wmsg_kernel<<<(512 * HID + 255) / 256, 256, 0, stream>>>(edge_W, Wmsg, 512 * HID);
    pack_wgru_kernel<<<(512 * 256 + 255) / 256, 256, 0, stream>>>(w_ih, w_hh, Wgru);

    // CSR build
    hist_kernel<<<(E + 255) / 256, 256, 0, stream>>>(dst, deg, E);
    scan_blocks_kernel<<<nb, 256, 0, stream>>>(deg, rowptr, blocksum, M);
    scan_top_kernel<<<1, 256, 0, stream>>>(blocksum, blockoff, nb);
    finalize_kernel<<<(M + 255) / 256, 256, 0, stream>>>(rowptr, blockoff, cursor, M);
    fill_kernel<<<(E + 255) / 256, 256, 0, stream>>>(src, dst, edge_type, cursor, csr, E);

    dim3 ggrid((M + 127) / 128, 4);
    // Y = hbf @ Wmsg^T
    gemm_y<<<ggrid, 256, 0, stream>>>(hbf, Wmsg, Ybf, M);

    // agg gather-reduce + bias -> bf16
    gather_kernel<<<(M + 3) / 4, 256, 0, stream>>>(rowptr, deg, csr, Ybf, edge_b, aggbf, M);

    // fused GRU GEMM + gates -> out
    gemm_gru<<<ggrid, 256, 0, stream>>>(Wgru, aggbf, hbf, node_states, b_ih, b_hh, (float*)d_out, M);
}

// Round 4
// 305.952 us; speedup vs baseline: 2.4401x; 1.0336x over previous
//
#include <hip/hip_runtime.h>

// ---------------------------------------------------------------------------
// GGNN message passing, MI355X/gfx950.  Round 4: commute gather with the
// message GEMM and kill all operand re-reads.
//
//   agg[n] = sum_t W_t @ (sum_{e: dst=n, t_e=t} h[src_e]) + cnt[n,t]*b_t
//   -> gather_s: CSR gather of raw hbf rows into S[n, t*128+k] (random-read
//      working set 12.8MB hbf, L2-class, vs R3's 51.2MB Y) + counts.
//   -> agg_gemm: [M,512] @ Wcat[128,512]^T, all 128 out cols per block
//      (S read ONCE), bias fused via counts in epilogue.
//   -> gemm_gru: C' = Wg[512x256] @ X[Mx256]^T with FULL gate dim per block
//      (64-node tiles): X read ONCE (R3 re-read it 4x -> 82us, MfmaUtil 6%).
//      One lane's 4 acc regs = (r,z,i_n,h_n) of one (node,j); GRU epilogue
//      writes out directly.
// ---------------------------------------------------------------------------

typedef __attribute__((ext_vector_type(8))) short short8;
typedef __attribute__((ext_vector_type(4))) float floatx4;

#define HID 128
#define NTY 4

__device__ __forceinline__ unsigned short f2bf(float f) {
    unsigned int u = __float_as_uint(f);
    unsigned int r = (u + 0x7fffu + ((u >> 16) & 1u)) >> 16;  // RNE
    return (unsigned short)r;
}
__device__ __forceinline__ float bf2f(unsigned int lo16) {
    return __uint_as_float(lo16 << 16);
}

// ---- prep kernels ---------------------------------------------------------

__global__ void cvt_h_kernel(const float* __restrict__ h, unsigned short* __restrict__ hbf, int total4) {
    int i = blockIdx.x * blockDim.x + threadIdx.x;
    if (i >= total4) return;
    float4 v = ((const float4*)h)[i];
    uint2 o;
    o.x = (unsigned int)f2bf(v.x) | ((unsigned int)f2bf(v.y) << 16);
    o.y = (unsigned int)f2bf(v.z) | ((unsigned int)f2bf(v.w) << 16);
    ((uint2*)hbf)[i] = o;
}

// Wcat[j][t*128+k] = edge_W[t][j][k]   (128 x 512 bf16)
__global__ void pack_wcat_kernel(const float* __restrict__ W, unsigned short* __restrict__ Wc) {
    int idx = blockIdx.x * blockDim.x + threadIdx.x;  // 128*512
    if (idx >= 128 * 512) return;
    int j = idx >> 9, rem = idx & 511;
    int t = rem >> 7, k = rem & 127;
    Wc[idx] = f2bf(W[(t * HID + j) * HID + k]);
}

// Wg [512][256]: rows 4j+{0,1,2,3} = r|z|i_n|h_n for out col j
__global__ void pack_wgru_kernel(const float* __restrict__ w_ih, const float* __restrict__ w_hh,
                                 unsigned short* __restrict__ Wg) {
    int idx = blockIdx.x * blockDim.x + threadIdx.x;  // 512*256
    if (idx >= 512 * 256) return;
    int row = idx >> 8, k = idx & 255;
    int j = row >> 2, g = row & 3;
    float v = 0.0f;
    if (g == 0) v = (k < 128) ? w_ih[j * 128 + k]         : w_hh[j * 128 + (k - 128)];
    else if (g == 1) v = (k < 128) ? w_ih[(128 + j) * 128 + k] : w_hh[(128 + j) * 128 + (k - 128)];
    else if (g == 2) v = (k < 128) ? w_ih[(256 + j) * 128 + k] : 0.0f;
    else             v = (k < 128) ? 0.0f : w_hh[(256 + j) * 128 + (k - 128)];
    Wg[idx] = f2bf(v);
}

// ---- CSR construction -----------------------------------------------------

__global__ void hist_kernel(const int* __restrict__ dst, int* __restrict__ deg, int E) {
    int e = blockIdx.x * blockDim.x + threadIdx.x;
    if (e < E) atomicAdd(&deg[dst[e]], 1);
}

__global__ void scan_blocks_kernel(const int* __restrict__ deg, int* __restrict__ rowptr,
                                   int* __restrict__ blocksum, int N) {
    __shared__ int s[256];
    int t = threadIdx.x;
    int i = blockIdx.x * 256 + t;
    int v = (i < N) ? deg[i] : 0;
    s[t] = v;
    __syncthreads();
#pragma unroll
    for (int off = 1; off < 256; off <<= 1) {
        int x = (t >= off) ? s[t - off] : 0;
        __syncthreads();
        s[t] += x;
        __syncthreads();
    }
    if (i < N) rowptr[i] = s[t] - v;  // exclusive
    if (t == 255) blocksum[blockIdx.x] = s[t];
}

__global__ void scan_top_kernel(const int* __restrict__ blocksum, int* __restrict__ blockoff, int nb) {
    __shared__ int s[256];
    int t = threadIdx.x;
    int v = (t < nb) ? blocksum[t] : 0;
    s[t] = v;
    __syncthreads();
#pragma unroll
    for (int off = 1; off < 256; off <<= 1) {
        int x = (t >= off) ? s[t - off] : 0;
        __syncthreads();
        s[t] += x;
        __syncthreads();
    }
    if (t < nb) blockoff[t] = s[t] - v;
}

__global__ void finalize_kernel(int* __restrict__ rowptr, const int* __restrict__ blockoff,
                                int* __restrict__ cursor, int N) {
    int i = blockIdx.x * blockDim.x + threadIdx.x;
    if (i >= N) return;
    int r = rowptr[i] + blockoff[i >> 8];
    rowptr[i] = r;
    cursor[i] = r;
}

__global__ void fill_kernel(const int* __restrict__ src, const int* __restrict__ dst,
                            const int* __restrict__ ety, int* __restrict__ cursor,
                            int* __restrict__ csr, int E) {
    int e = blockIdx.x * blockDim.x + threadIdx.x;
    if (e >= E) return;
    int pos = atomicAdd(&cursor[dst[e]], 1);
    csr[pos] = (src[e] << 2) | ety[e];
}

// ---- gather_s: S[n, t*128 + :] = sum of hbf rows of type t; counts --------
// One wave per node; lane owns cols {2l,2l+1} (one uint of the hbf row).
// 4x unrolled: 4 independent loads in flight.

__global__ void gather_s_kernel(const int* __restrict__ rowptr, const int* __restrict__ deg,
                                const int* __restrict__ csr, const unsigned int* __restrict__ hbu,
                                float4* __restrict__ cnt4, unsigned int* __restrict__ Su, int N) {
    int w = blockIdx.x * (blockDim.x >> 6) + (threadIdx.x >> 6);
    if (w >= N) return;
    int lane = threadIdx.x & 63;
    int start = rowptr[w];
    int end = start + deg[w];
    float a00 = 0.f, a01 = 0.f, a10 = 0.f, a11 = 0.f;
    float a20 = 0.f, a21 = 0.f, a30 = 0.f, a31 = 0.f;
    unsigned int cpack = 0;
    int e = start;
    for (; e + 4 <= end; e += 4) {
        int p0 = csr[e], p1 = csr[e + 1], p2 = csr[e + 2], p3 = csr[e + 3];
        unsigned int u0 = hbu[(size_t)(p0 >> 2) * 64 + lane];
        unsigned int u1 = hbu[(size_t)(p1 >> 2) * 64 + lane];
        unsigned int u2 = hbu[(size_t)(p2 >> 2) * 64 + lane];
        unsigned int u3 = hbu[(size_t)(p3 >> 2) * 64 + lane];
        cpack += (1u << ((p0 & 3) << 3)) + (1u << ((p1 & 3) << 3))
               + (1u << ((p2 & 3) << 3)) + (1u << ((p3 & 3) << 3));
        {
            int t = p0 & 3; float v0 = bf2f(u0 & 0xffffu), v1 = bf2f(u0 >> 16);
            a00 += (t == 0) ? v0 : 0.f; a01 += (t == 0) ? v1 : 0.f;
            a10 += (t == 1) ? v0 : 0.f; a11 += (t == 1) ? v1 : 0.f;
            a20 += (t == 2) ? v0 : 0.f; a21 += (t == 2) ? v1 : 0.f;
            a30 += (t == 3) ? v0 : 0.f; a31 += (t == 3) ? v1 : 0.f;
        }
        {
            int t = p1 & 3; float v0 = bf2f(u1 & 0xffffu), v1 = bf2f(u1 >> 16);
            a00 += (t == 0) ? v0 : 0.f; a01 += (t == 0) ? v1 : 0.f;
            a10 += (t == 1) ? v0 : 0.f; a11 += (t == 1) ? v1 : 0.f;
            a20 += (t == 2) ? v0 : 0.f; a21 += (t == 2) ? v1 : 0.f;
            a30 += (t == 3) ? v0 : 0.f; a31 += (t == 3) ? v1 : 0.f;
        }
        {
            int t = p2 & 3; float v0 = bf2f(u2 & 0xffffu), v1 = bf2f(u2 >> 16);
            a00 += (t == 0) ? v0 : 0.f; a01 += (t == 0) ? v1 : 0.f;
            a10 += (t == 1) ? v0 : 0.f; a11 += (t == 1) ? v1 : 0.f;
            a20 += (t == 2) ? v0 : 0.f; a21 += (t == 2) ? v1 : 0.f;
            a30 += (t == 3) ? v0 : 0.f; a31 += (t == 3) ? v1 : 0.f;
        }
        {
            int t = p3 & 3; float v0 = bf2f(u3 & 0xffffu), v1 = bf2f(u3 >> 16);
            a00 += (t == 0) ? v0 : 0.f; a01 += (t == 0) ? v1 : 0.f;
            a10 += (t == 1) ? v0 : 0.f; a11 += (t == 1) ? v1 : 0.f;
            a20 += (t == 2) ? v0 : 0.f; a21 += (t == 2) ? v1 : 0.f;
            a30 += (t == 3) ? v0 : 0.f; a31 += (t == 3) ? v1 : 0.f;
        }
    }
    for (; e < end; ++e) {
        int pk = csr[e];
        unsigned int u = hbu[(size_t)(pk >> 2) * 64 + lane];
        cpack += 1u << ((pk & 3) << 3);
        int t = pk & 3; float v0 = bf2f(u & 0xffffu), v1 = bf2f(u >> 16);
        a00 += (t == 0) ? v0 : 0.f; a01 += (t == 0) ? v1 : 0.f;
        a10 += (t == 1) ? v0 : 0.f; a11 += (t == 1) ? v1 : 0.f;
        a20 += (t == 2) ? v0 : 0.f; a21 += (t == 2) ? v1 : 0.f;
        a30 += (t == 3) ? v0 : 0.f; a31 += (t == 3) ? v1 : 0.f;
    }
    size_t base = (size_t)w * 256 + lane;
    Su[base]       = (unsigned int)f2bf(a00) | ((unsigned int)f2bf(a01) << 16);
    Su[base + 64]  = (unsigned int)f2bf(a10) | ((unsigned int)f2bf(a11) << 16);
    Su[base + 128] = (unsigned int)f2bf(a20) | ((unsigned int)f2bf(a21) << 16);
    Su[base + 192] = (unsigned int)f2bf(a30) | ((unsigned int)f2bf(a31) << 16);
    if (lane == 0)
        cnt4[w] = make_float4((float)(cpack & 255u), (float)((cpack >> 8) & 255u),
                              (float)((cpack >> 16) & 255u), (float)(cpack >> 24));
}

// ---- agg_gemm: aggbf[M x 128] = S[M x 512] @ Wcat[128 x 512]^T + bias -----
// All 128 out cols per block -> S read once.  Wcat (128KB) direct from L2.

__global__ __launch_bounds__(256) void agg_gemm(const unsigned short* __restrict__ S,
                                                const unsigned short* __restrict__ Wc,
                                                const float4* __restrict__ cnt4,
                                                const float* __restrict__ eb,
                                                unsigned short* __restrict__ aggbf, int M) {
    __shared__ __align__(16) unsigned short Ss[128][136];
    const int tid = threadIdx.x;
    const int m0 = blockIdx.x * 128;
    const int lane = tid & 63, wave = tid >> 6;
    const int wm = wave >> 1, wn = wave & 1;
    const int lm = lane & 15, quad = lane >> 4;

    floatx4 acc[4][4];
#pragma unroll
    for (int a = 0; a < 4; ++a)
#pragma unroll
        for (int b = 0; b < 4; ++b) acc[a][b] = (floatx4){0.f, 0.f, 0.f, 0.f};

    for (int c = 0; c < 4; ++c) {  // K = 512, BK = 128
        {
            int rr = tid >> 4;
            int cc = (tid & 15) * 8;
#pragma unroll
            for (int p = 0; p < 8; ++p) {
                int r = rr + p * 16;
                int gm = m0 + r;
                uint4 v = {0u, 0u, 0u, 0u};
                if (gm < M) v = *(const uint4*)(S + (size_t)gm * 512 + c * 128 + cc);
                *(uint4*)&Ss[r][cc] = v;
            }
        }
        __syncthreads();
#pragma unroll
        for (int s = 0; s < 4; ++s) {
            short8 af[4], bfr[4];
#pragma unroll
            for (int mi = 0; mi < 4; ++mi)
                af[mi] = *(const short8*)&Ss[wm * 64 + mi * 16 + lm][s * 32 + quad * 8];
#pragma unroll
            for (int ni = 0; ni < 4; ++ni) {
                int j = wn * 64 + ni * 16 + lm;
                bfr[ni] = *(const short8*)(Wc + (size_t)j * 512 + c * 128 + s * 32 + quad * 8);
            }
#pragma unroll
            for (int mi = 0; mi < 4; ++mi)
#pragma unroll
                for (int ni = 0; ni < 4; ++ni)
                    acc[mi][ni] = __builtin_amdgcn_mfma_f32_16x16x32_bf16(af[mi], bfr[ni], acc[mi][ni], 0, 0, 0);
        }
        __syncthreads();
    }
    // epilogue: row(node) = m0 + wm*64 + mi*16 + quad*4 + r, col j = wn*64+ni*16+lm
#pragma unroll
    for (int mi = 0; mi < 4; ++mi) {
        int row_b = m0 + wm * 64 + mi * 16 + quad * 4;
#pragma unroll
        for (int r = 0; r < 4; ++r) {
            int node = row_b + r;
            if (node >= M) continue;
            float4 c4 = cnt4[node];
#pragma unroll
            for (int ni = 0; ni < 4; ++ni) {
                int j = wn * 64 + ni * 16 + lm;
                float v = acc[mi][ni][r];
                v += c4.x * eb[j] + c4.y * eb[HID + j] + c4.z * eb[2 * HID + j] + c4.w * eb[3 * HID + j];
                aggbf[(size_t)node * HID + j] = f2bf(v);
            }
        }
    }
}

// ---- gemm_gru fused: C'[512 x M] = Wg[512x256] @ X[Mx256]^T ---------------
// FULL gate dim per block, 64-node tiles -> X read once.  Wave wm owns gate
// rows [wm*128, wm*128+128).  acc[mi][ni][0..3] = (r,z,i_n,h_n) of (node,j).

__global__ __launch_bounds__(256, 2) void gemm_gru(const unsigned short* __restrict__ Wg,
                                                   const unsigned short* __restrict__ aggbf,
                                                   const unsigned short* __restrict__ hbf,
                                                   const float* __restrict__ h,
                                                   const float* __restrict__ b_ih,
                                                   const float* __restrict__ b_hh,
                                                   float* __restrict__ out, int M) {
    __shared__ __align__(16) unsigned short Xs[64][136];
    const int tid = threadIdx.x;
    const int n0 = blockIdx.x * 64;  // node tile
    const int lane = tid & 63, wm = tid >> 6;
    const int lm = lane & 15, quad = lane >> 4;

    floatx4 acc[8][4];
#pragma unroll
    for (int a = 0; a < 8; ++a)
#pragma unroll
        for (int b = 0; b < 4; ++b) acc[a][b] = (floatx4){0.f, 0.f, 0.f, 0.f};

    for (int c = 0; c < 2; ++c) {
        const unsigned short* Xp = c ? hbf : aggbf;
        {
            int rr = tid >> 4;         // 0..15
            int cc = (tid & 15) * 8;   // 0..120
#pragma unroll
            for (int p = 0; p < 4; ++p) {
                int r = rr + p * 16;   // 0..63
                int gn = n0 + r;
                uint4 v = {0u, 0u, 0u, 0u};
                if (gn < M) v = *(const uint4*)(Xp + (size_t)gn * HID + cc);
                *(uint4*)&Xs[r][cc] = v;
            }
        }
        __syncthreads();
#pragma unroll
        for (int s = 0; s < 4; ++s) {
            short8 bfr[4];
#pragma unroll
            for (int ni = 0; ni < 4; ++ni)
                bfr[ni] = *(const short8*)&Xs[ni * 16 + lm][s * 32 + quad * 8];
            short8 af[8];
#pragma unroll
            for (int mi = 0; mi < 8; ++mi) {
                int rowg = wm * 128 + mi * 16 + lm;
                af[mi] = *(const short8*)(Wg + (size_t)rowg * 256 + c * 128 + s * 32 + quad * 8);
            }
#pragma unroll
            for (int mi = 0; mi < 8; ++mi)
#pragma unroll
                for (int ni = 0; ni < 4; ++ni)
                    acc[mi][ni] = __builtin_amdgcn_mfma_f32_16x16x32_bf16(af[mi], bfr[ni], acc[mi][ni], 0, 0, 0);
        }
        __syncthreads();
    }

    // epilogue: gate row = wm*128 + mi*16 + quad*4 + g  ->  j = wm*32+mi*4+quad
#pragma unroll
    for (int mi = 0; mi < 8; ++mi) {
        int j = wm * 32 + mi * 4 + quad;  // 0..127
        float brj = b_ih[j] + b_hh[j];
        float bzj = b_ih[128 + j] + b_hh[128 + j];
        float bin = b_ih[256 + j];
        float bhn = b_hh[256 + j];
#pragma unroll
        for (int ni = 0; ni < 4; ++ni) {
            int node = n0 + ni * 16 + lm;
            if (node < M) {
                float g0 = acc[mi][ni][0], g1 = acc[mi][ni][1];
                float g2 = acc[mi][ni][2], g3 = acc[mi][ni][3];
                float r = 1.0f / (1.0f + __expf(-(g0 + brj)));
                float z = 1.0f / (1.0f + __expf(-(g1 + bzj)));
                float nn = tanhf(g2 + bin + r * (g3 + bhn));
                float hv = h[(size_t)node * HID + j];
                out[(size_t)node * HID + j] = (1.0f - z) * nn + z * hv;
            }
        }
    }
}

// ---------------------------------------------------------------------------

extern "C" void kernel_launch(void* const* d_in, const int* in_sizes, int n_in,
                              void* d_out, int out_size, void* d_ws, size_t ws_size,
                              hipStream_t stream) {
    const float* node_states = (const float*)d_in[0];
    const int*   edge_index  = (const int*)d_in[1];
    const int*   edge_type   = (const int*)d_in[2];
    const float* edge_W      = (const float*)d_in[3];
    const float* edge_b      = (const float*)d_in[4];
    const float* w_ih        = (const float*)d_in[5];
    const float* w_hh        = (const float*)d_in[6];
    const float* b_ih        = (const float*)d_in[7];
    const float* b_hh        = (const float*)d_in[8];

    const int M = in_sizes[0] / HID;      // 50000 nodes
    const int E = in_sizes[1] / 2;        // 625000 edges
    const int* src = edge_index;
    const int* dst = edge_index + E;

    // workspace layout (~81 MB)
    char* ws = (char*)d_ws;
    size_t off = 0;
    unsigned short* hbf   = (unsigned short*)(ws + off); off += (size_t)M * HID * 2;    // 12.8MB
    unsigned short* aggbf = (unsigned short*)(ws + off); off += (size_t)M * HID * 2;    // 12.8MB
    unsigned short* S     = (unsigned short*)(ws + off); off += (size_t)M * 512 * 2;    // 51.2MB
    unsigned short* Wcat  = (unsigned short*)(ws + off); off += (size_t)128 * 512 * 2;  // 128KB
    unsigned short* Wgru  = (unsigned short*)(ws + off); off += (size_t)512 * 256 * 2;  // 256KB
    float*          cnt4  = (float*)(ws + off);          off += (size_t)M * 4 * 4;      // 800KB
    int* deg      = (int*)(ws + off); off += (size_t)M * 4;
    int* rowptr   = (int*)(ws + off); off += (size_t)M * 4;
    int* cursor   = (int*)(ws + off); off += (size_t)M * 4;
    int* blocksum = (int*)(ws + off); off += 256 * 4;
    int* blockoff = (int*)(ws + off); off += 256 * 4;
    int* csr      = (int*)(ws + off); off += (size_t)E * 4;

    const int nb = (M + 255) / 256;  // 196 <= 256

    hipMemsetAsync(deg, 0, (size_t)M * 4, stream);

    int t4 = M * HID / 4;
    cvt_h_kernel<<<(t4 + 255) / 256, 256, 0, stream>>>(node_states, hbf, t4);
    pack_wcat_kernel<<<(128 * 512 + 255) / 256, 256, 0, stream>>>(edge_W, Wcat);
    pack_wgru_kernel<<<(512 * 256 + 255) / 256, 256, 0, stream>>>(w_ih, w_hh, Wgru);

    // CSR build
    hist_kernel<<<(E + 255) / 256, 256, 0, stream>>>(dst, deg, E);
    scan_blocks_kernel<<<nb, 256, 0, stream>>>(deg, rowptr, blocksum, M);
    scan_top_kernel<<<1, 256, 0, stream>>>(blocksum, blockoff, nb);
    finalize_kernel<<<(M + 255) / 256, 256, 0, stream>>>(rowptr, blockoff, cursor, M);
    fill_kernel<<<(E + 255) / 256, 256, 0, stream>>>(src, dst, edge_type, cursor, csr, E);

    // S[n, t*128+:] = sum of same-type neighbor hbf rows; counts
    gather_s_kernel<<<(M + 3) / 4, 256, 0, stream>>>(rowptr, deg, csr, (const unsigned int*)hbf,
                                                     (float4*)cnt4, (unsigned int*)S, M);

    // aggbf = S @ Wcat^T + cnt*b   (K=512, S read once)
    agg_gemm<<<(M + 127) / 128, 256, 0, stream>>>(S, Wcat, (const float4*)cnt4, edge_b, aggbf, M);

    // fused GRU GEMM + gates -> out  (full gate dim per block, X read once)
    gemm_gru<<<(M + 63) / 64, 256, 0, stream>>>(Wgru, aggbf, hbf, node_states, b_ih, b_hh,
                                                (float*)d_out, M);
}

// Round 5
// 299.603 us; speedup vs baseline: 2.4918x; 1.0212x over previous
//
#include <hip/hip_runtime.h>

// ---------------------------------------------------------------------------
// GGNN message passing, MI355X/gfx950.  Round 5: kill write amplification.
// R4 counters: gemm_gru WRITE_SIZE 94.4MB for 25.6MB of output -> scalar 4B
// stores at lane-stride 512B cause sector-granular writeback.  Fix: epilogue
// results staged in LDS, then coalesced wide stores.  Same fix in agg_gemm
// (2B scalar aggbf stores).  gemm_gru also returns to 64-reg accumulators
// (2 gate-halves per grid.y) to relieve register pressure.
//
// Dataflow (unchanged from R4):
//   S[n, t*128+k] = sum_{e: dst=n, t_e=t} hbf[src_e][k]   (CSR gather)
//   aggbf = S @ Wcat^T + cnt*b                            (K=512 GEMM)
//   out   = GRU(aggbf, h) via C' = Wg[512x256] @ [aggbf|hbf]^T, gate rows
//           4j+{r,z,i_n,h_n} -> one lane's 4 acc regs, fused nonlinearity.
// ---------------------------------------------------------------------------

typedef __attribute__((ext_vector_type(8))) short short8;
typedef __attribute__((ext_vector_type(4))) float floatx4;

#define HID 128
#define NTY 4

__device__ __forceinline__ unsigned short f2bf(float f) {
    unsigned int u = __float_as_uint(f);
    unsigned int r = (u + 0x7fffu + ((u >> 16) & 1u)) >> 16;  // RNE
    return (unsigned short)r;
}
__device__ __forceinline__ float bf2f(unsigned int lo16) {
    return __uint_as_float(lo16 << 16);
}

// ---- prep kernels ---------------------------------------------------------

__global__ void cvt_h_kernel(const float* __restrict__ h, unsigned short* __restrict__ hbf, int total4) {
    int i = blockIdx.x * blockDim.x + threadIdx.x;
    if (i >= total4) return;
    float4 v = ((const float4*)h)[i];
    uint2 o;
    o.x = (unsigned int)f2bf(v.x) | ((unsigned int)f2bf(v.y) << 16);
    o.y = (unsigned int)f2bf(v.z) | ((unsigned int)f2bf(v.w) << 16);
    ((uint2*)hbf)[i] = o;
}

// Wcat[j][t*128+k] = edge_W[t][j][k]   (128 x 512 bf16)
__global__ void pack_wcat_kernel(const float* __restrict__ W, unsigned short* __restrict__ Wc) {
    int idx = blockIdx.x * blockDim.x + threadIdx.x;  // 128*512
    if (idx >= 128 * 512) return;
    int j = idx >> 9, rem = idx & 511;
    int t = rem >> 7, k = rem & 127;
    Wc[idx] = f2bf(W[(t * HID + j) * HID + k]);
}

// Wg [512][256]: rows 4j+{0,1,2,3} = r|z|i_n|h_n for out col j
__global__ void pack_wgru_kernel(const float* __restrict__ w_ih, const float* __restrict__ w_hh,
                                 unsigned short* __restrict__ Wg) {
    int idx = blockIdx.x * blockDim.x + threadIdx.x;  // 512*256
    if (idx >= 512 * 256) return;
    int row = idx >> 8, k = idx & 255;
    int j = row >> 2, g = row & 3;
    float v = 0.0f;
    if (g == 0) v = (k < 128) ? w_ih[j * 128 + k]         : w_hh[j * 128 + (k - 128)];
    else if (g == 1) v = (k < 128) ? w_ih[(128 + j) * 128 + k] : w_hh[(128 + j) * 128 + (k - 128)];
    else if (g == 2) v = (k < 128) ? w_ih[(256 + j) * 128 + k] : 0.0f;
    else             v = (k < 128) ? 0.0f : w_hh[(256 + j) * 128 + (k - 128)];
    Wg[idx] = f2bf(v);
}

// ---- CSR construction -----------------------------------------------------

__global__ void hist_kernel(const int* __restrict__ dst, int* __restrict__ deg, int E) {
    int e = blockIdx.x * blockDim.x + threadIdx.x;
    if (e < E) atomicAdd(&deg[dst[e]], 1);
}

__global__ void scan_blocks_kernel(const int* __restrict__ deg, int* __restrict__ rowptr,
                                   int* __restrict__ blocksum, int N) {
    __shared__ int s[256];
    int t = threadIdx.x;
    int i = blockIdx.x * 256 + t;
    int v = (i < N) ? deg[i] : 0;
    s[t] = v;
    __syncthreads();
#pragma unroll
    for (int off = 1; off < 256; off <<= 1) {
        int x = (t >= off) ? s[t - off] : 0;
        __syncthreads();
        s[t] += x;
        __syncthreads();
    }
    if (i < N) rowptr[i] = s[t] - v;  // exclusive
    if (t == 255) blocksum[blockIdx.x] = s[t];
}

__global__ void scan_top_kernel(const int* __restrict__ blocksum, int* __restrict__ blockoff, int nb) {
    __shared__ int s[256];
    int t = threadIdx.x;
    int v = (t < nb) ? blocksum[t] : 0;
    s[t] = v;
    __syncthreads();
#pragma unroll
    for (int off = 1; off < 256; off <<= 1) {
        int x = (t >= off) ? s[t - off] : 0;
        __syncthreads();
        s[t] += x;
        __syncthreads();
    }
    if (t < nb) blockoff[t] = s[t] - v;
}

__global__ void finalize_kernel(int* __restrict__ rowptr, const int* __restrict__ blockoff,
                                int* __restrict__ cursor, int N) {
    int i = blockIdx.x * blockDim.x + threadIdx.x;
    if (i >= N) return;
    int r = rowptr[i] + blockoff[i >> 8];
    rowptr[i] = r;
    cursor[i] = r;
}

__global__ void fill_kernel(const int* __restrict__ src, const int* __restrict__ dst,
                            const int* __restrict__ ety, int* __restrict__ cursor,
                            int* __restrict__ csr, int E) {
    int e = blockIdx.x * blockDim.x + threadIdx.x;
    if (e >= E) return;
    int pos = atomicAdd(&cursor[dst[e]], 1);
    csr[pos] = (src[e] << 2) | ety[e];
}

// ---- gather_s: S[n, t*128 + :] = sum of hbf rows of type t; counts --------
// One wave per node; lane owns cols {2l,2l+1}.  8x + 4x unrolled (MLP).

__device__ __forceinline__ void acc_typed(int pk, unsigned int u,
                                          float& a00, float& a01, float& a10, float& a11,
                                          float& a20, float& a21, float& a30, float& a31) {
    int t = pk & 3;
    float v0 = bf2f(u & 0xffffu), v1 = bf2f(u >> 16);
    a00 += (t == 0) ? v0 : 0.f; a01 += (t == 0) ? v1 : 0.f;
    a10 += (t == 1) ? v0 : 0.f; a11 += (t == 1) ? v1 : 0.f;
    a20 += (t == 2) ? v0 : 0.f; a21 += (t == 2) ? v1 : 0.f;
    a30 += (t == 3) ? v0 : 0.f; a31 += (t == 3) ? v1 : 0.f;
}

__global__ void gather_s_kernel(const int* __restrict__ rowptr, const int* __restrict__ deg,
                                const int* __restrict__ csr, const unsigned int* __restrict__ hbu,
                                float4* __restrict__ cnt4, unsigned int* __restrict__ Su, int N) {
    int w = blockIdx.x * (blockDim.x >> 6) + (threadIdx.x >> 6);
    if (w >= N) return;
    int lane = threadIdx.x & 63;
    int start = rowptr[w];
    int end = start + deg[w];
    float a00 = 0.f, a01 = 0.f, a10 = 0.f, a11 = 0.f;
    float a20 = 0.f, a21 = 0.f, a30 = 0.f, a31 = 0.f;
    unsigned int cpack = 0;
    int e = start;
    for (; e + 8 <= end; e += 8) {
        int p[8];
        unsigned int u[8];
#pragma unroll
        for (int i = 0; i < 8; ++i) p[i] = csr[e + i];
#pragma unroll
        for (int i = 0; i < 8; ++i) u[i] = hbu[(size_t)(p[i] >> 2) * 64 + lane];
#pragma unroll
        for (int i = 0; i < 8; ++i) {
            cpack += 1u << ((p[i] & 3) << 3);
            acc_typed(p[i], u[i], a00, a01, a10, a11, a20, a21, a30, a31);
        }
    }
    for (; e + 4 <= end; e += 4) {
        int p[4];
        unsigned int u[4];
#pragma unroll
        for (int i = 0; i < 4; ++i) p[i] = csr[e + i];
#pragma unroll
        for (int i = 0; i < 4; ++i) u[i] = hbu[(size_t)(p[i] >> 2) * 64 + lane];
#pragma unroll
        for (int i = 0; i < 4; ++i) {
            cpack += 1u << ((p[i] & 3) << 3);
            acc_typed(p[i], u[i], a00, a01, a10, a11, a20, a21, a30, a31);
        }
    }
    for (; e < end; ++e) {
        int pk = csr[e];
        unsigned int u = hbu[(size_t)(pk >> 2) * 64 + lane];
        cpack += 1u << ((pk & 3) << 3);
        acc_typed(pk, u, a00, a01, a10, a11, a20, a21, a30, a31);
    }
    size_t base = (size_t)w * 256 + lane;
    Su[base]       = (unsigned int)f2bf(a00) | ((unsigned int)f2bf(a01) << 16);
    Su[base + 64]  = (unsigned int)f2bf(a10) | ((unsigned int)f2bf(a11) << 16);
    Su[base + 128] = (unsigned int)f2bf(a20) | ((unsigned int)f2bf(a21) << 16);
    Su[base + 192] = (unsigned int)f2bf(a30) | ((unsigned int)f2bf(a31) << 16);
    if (lane == 0)
        cnt4[w] = make_float4((float)(cpack & 255u), (float)((cpack >> 8) & 255u),
                              (float)((cpack >> 16) & 255u), (float)(cpack >> 24));
}

// ---- agg_gemm: aggbf[M x 128] = S[M x 512] @ Wcat[128 x 512]^T + bias -----
// All 128 out cols per block -> S read once.  Wcat (128KB) direct from L2.
// Epilogue: results re-staged into (dead) Ss LDS, then coalesced uint4 writes.

__global__ __launch_bounds__(256) void agg_gemm(const unsigned short* __restrict__ S,
                                                const unsigned short* __restrict__ Wc,
                                                const float4* __restrict__ cnt4,
                                                const float* __restrict__ eb,
                                                unsigned short* __restrict__ aggbf, int M) {
    __shared__ __align__(16) unsigned short Ss[128][136];
    const int tid = threadIdx.x;
    const int m0 = blockIdx.x * 128;
    const int lane = tid & 63, wave = tid >> 6;
    const int wm = wave >> 1, wn = wave & 1;
    const int lm = lane & 15, quad = lane >> 4;

    floatx4 acc[4][4];
#pragma unroll
    for (int a = 0; a < 4; ++a)
#pragma unroll
        for (int b = 0; b < 4; ++b) acc[a][b] = (floatx4){0.f, 0.f, 0.f, 0.f};

    for (int c = 0; c < 4; ++c) {  // K = 512, BK = 128
        {
            int rr = tid >> 4;
            int cc = (tid & 15) * 8;
#pragma unroll
            for (int p = 0; p < 8; ++p) {
                int r = rr + p * 16;
                int gm = m0 + r;
                uint4 v = {0u, 0u, 0u, 0u};
                if (gm < M) v = *(const uint4*)(S + (size_t)gm * 512 + c * 128 + cc);
                *(uint4*)&Ss[r][cc] = v;
            }
        }
        __syncthreads();
#pragma unroll
        for (int s = 0; s < 4; ++s) {
            short8 af[4], bfr[4];
#pragma unroll
            for (int mi = 0; mi < 4; ++mi)
                af[mi] = *(const short8*)&Ss[wm * 64 + mi * 16 + lm][s * 32 + quad * 8];
#pragma unroll
            for (int ni = 0; ni < 4; ++ni) {
                int j = wn * 64 + ni * 16 + lm;
                bfr[ni] = *(const short8*)(Wc + (size_t)j * 512 + c * 128 + s * 32 + quad * 8);
            }
#pragma unroll
            for (int mi = 0; mi < 4; ++mi)
#pragma unroll
                for (int ni = 0; ni < 4; ++ni)
                    acc[mi][ni] = __builtin_amdgcn_mfma_f32_16x16x32_bf16(af[mi], bfr[ni], acc[mi][ni], 0, 0, 0);
        }
        __syncthreads();
    }
    // epilogue: stage bf16 results into Ss (dead after last sync), coalesced write
#pragma unroll
    for (int mi = 0; mi < 4; ++mi) {
        int row_b = wm * 64 + mi * 16 + quad * 4;
#pragma unroll
        for (int r = 0; r < 4; ++r) {
            int lrow = row_b + r;
            int node = m0 + lrow;
            float4 c4 = (node < M) ? cnt4[node] : make_float4(0.f, 0.f, 0.f, 0.f);
#pragma unroll
            for (int ni = 0; ni < 4; ++ni) {
                int j = wn * 64 + ni * 16 + lm;
                float v = acc[mi][ni][r];
                v += c4.x * eb[j] + c4.y * eb[HID + j] + c4.z * eb[2 * HID + j] + c4.w * eb[3 * HID + j];
                Ss[lrow][j] = f2bf(v);
            }
        }
    }
    __syncthreads();
    {
        int row = tid >> 1;              // 0..127
        int half = (tid & 1) * 64;       // shorts
        int node = m0 + row;
        if (node < M) {
#pragma unroll
            for (int i = 0; i < 8; ++i)
                *(uint4*)(aggbf + (size_t)node * HID + half + i * 8) = *(const uint4*)&Ss[row][half + i * 8];
        }
    }
}

// ---- gemm_gru fused: C'[512 x M] = Wg[512x256] @ X[Mx256]^T ---------------
// grid.y = gate-half gh (256 gate rows = 64 j's); 64-node tiles; 4 waves,
// each wave 64 gate rows x 64 nodes (acc 4x4 = 64 regs, no pressure).
// acc[mi][ni][0..3] = (r,z,i_n,h_n) of (node, j).  Results go through a
// fp32 LDS tile for coalesced float4 out stores.

__global__ __launch_bounds__(256) void gemm_gru(const unsigned short* __restrict__ Wg,
                                                const unsigned short* __restrict__ aggbf,
                                                const unsigned short* __restrict__ hbf,
                                                const float* __restrict__ h,
                                                const float* __restrict__ b_ih,
                                                const float* __restrict__ b_hh,
                                                float* __restrict__ out, int M) {
    __shared__ __align__(16) unsigned short Xs[64][136];
    __shared__ __align__(16) float Outs[64][68];
    const int tid = threadIdx.x;
    const int n0 = blockIdx.x * 64;       // node tile
    const int gh = blockIdx.y;            // gate half: rows [gh*256, gh*256+256)
    const int lane = tid & 63, w = tid >> 6;
    const int lm = lane & 15, quad = lane >> 4;

    floatx4 acc[4][4];
#pragma unroll
    for (int a = 0; a < 4; ++a)
#pragma unroll
        for (int b = 0; b < 4; ++b) acc[a][b] = (floatx4){0.f, 0.f, 0.f, 0.f};

    for (int c = 0; c < 2; ++c) {
        const unsigned short* Xp = c ? hbf : aggbf;
        {
            int rr = tid >> 4;         // 0..15
            int cc = (tid & 15) * 8;   // 0..120
#pragma unroll
            for (int p = 0; p < 4; ++p) {
                int r = rr + p * 16;   // 0..63
                int gn = n0 + r;
                uint4 v = {0u, 0u, 0u, 0u};
                if (gn < M) v = *(const uint4*)(Xp + (size_t)gn * HID + cc);
                *(uint4*)&Xs[r][cc] = v;
            }
        }
        __syncthreads();
#pragma unroll
        for (int s = 0; s < 4; ++s) {
            short8 bfr[4];
#pragma unroll
            for (int ni = 0; ni < 4; ++ni)
                bfr[ni] = *(const short8*)&Xs[ni * 16 + lm][s * 32 + quad * 8];
            short8 af[4];
#pragma unroll
            for (int mi = 0; mi < 4; ++mi) {
                int rowg = gh * 256 + w * 64 + mi * 16 + lm;
                af[mi] = *(const short8*)(Wg + (size_t)rowg * 256 + c * 128 + s * 32 + quad * 8);
            }
#pragma unroll
            for (int mi = 0; mi < 4; ++mi)
#pragma unroll
                for (int ni = 0; ni < 4; ++ni)
                    acc[mi][ni] = __builtin_amdgcn_mfma_f32_16x16x32_bf16(af[mi], bfr[ni], acc[mi][ni], 0, 0, 0);
        }
        __syncthreads();
    }

    // epilogue: gate row = gh*256 + w*64 + mi*16 + quad*4 + g -> j = row>>2
#pragma unroll
    for (int mi = 0; mi < 4; ++mi) {
        int jl = w * 16 + mi * 4 + quad;  // 0..63 within half
        int j = gh * 64 + jl;             // 0..127
        float brj = b_ih[j] + b_hh[j];
        float bzj = b_ih[128 + j] + b_hh[128 + j];
        float bin = b_ih[256 + j];
        float bhn = b_hh[256 + j];
#pragma unroll
        for (int ni = 0; ni < 4; ++ni) {
            int lrow = ni * 16 + lm;
            int node = n0 + lrow;
            float g0 = acc[mi][ni][0], g1 = acc[mi][ni][1];
            float g2 = acc[mi][ni][2], g3 = acc[mi][ni][3];
            float r = 1.0f / (1.0f + __expf(-(g0 + brj)));
            float z = 1.0f / (1.0f + __expf(-(g1 + bzj)));
            float nn = tanhf(g2 + bin + r * (g3 + bhn));
            float hv = (node < M) ? h[(size_t)node * HID + j] : 0.f;
            Outs[lrow][jl] = (1.0f - z) * nn + z * hv;
        }
    }
    __syncthreads();
    // coalesced write: 64 nodes x 64 floats (256B contiguous per node)
    {
        int row = tid >> 2;              // 0..63
        int c0 = (tid & 3) * 16;         // 0..48
        int node = n0 + row;
        if (node < M) {
            float* dst = out + (size_t)node * HID + gh * 64 + c0;
#pragma unroll
            for (int i = 0; i < 4; ++i)
                *(float4*)(dst + i * 4) = *(const float4*)&Outs[row][c0 + i * 4];
        }
    }
}

// ---------------------------------------------------------------------------

extern "C" void kernel_launch(void* const* d_in, const int* in_sizes, int n_in,
                              void* d_out, int out_size, void* d_ws, size_t ws_size,
                              hipStream_t stream) {
    const float* node_states = (const float*)d_in[0];
    const int*   edge_index  = (const int*)d_in[1];
    const int*   edge_type   = (const int*)d_in[2];
    const float* edge_W      = (const float*)d_in[3];
    const float* edge_b      = (const float*)d_in[4];
    const float* w_ih        = (const float*)d_in[5];
    const float* w_hh        = (const float*)d_in[6];
    const float* b_ih        = (const float*)d_in[7];
    const float* b_hh        = (const float*)d_in[8];

    const int M = in_sizes[0] / HID;      // 50000 nodes
    const int E = in_sizes[1] / 2;        // 625000 edges
    const int* src = edge_index;
    const int* dst = edge_index + E;

    // workspace layout (~81 MB)
    char* ws = (char*)d_ws;
    size_t off = 0;
    unsigned short* hbf   = (unsigned short*)(ws + off); off += (size_t)M * HID * 2;    // 12.8MB
    unsigned short* aggbf = (unsigned short*)(ws + off); off += (size_t)M * HID * 2;    // 12.8MB
    unsigned short* S     = (unsigned short*)(ws + off); off += (size_t)M * 512 * 2;    // 51.2MB
    unsigned short* Wcat  = (unsigned short*)(ws + off); off += (size_t)128 * 512 * 2;  // 128KB
    unsigned short* Wgru  = (unsigned short*)(ws + off); off += (size_t)512 * 256 * 2;  // 256KB
    float*          cnt4  = (float*)(ws + off);          off += (size_t)M * 4 * 4;      // 800KB
    int* deg      = (int*)(ws + off); off += (size_t)M * 4;
    int* rowptr   = (int*)(ws + off); off += (size_t)M * 4;
    int* cursor   = (int*)(ws + off); off += (size_t)M * 4;
    int* blocksum = (int*)(ws + off); off += 256 * 4;
    int* blockoff = (int*)(ws + off); off += 256 * 4;
    int* csr      = (int*)(ws + off); off += (size_t)E * 4;

    const int nb = (M + 255) / 256;  // 196 <= 256

    hipMemsetAsync(deg, 0, (size_t)M * 4, stream);

    int t4 = M * HID / 4;
    cvt_h_kernel<<<(t4 + 255) / 256, 256, 0, stream>>>(node_states, hbf, t4);
    pack_wcat_kernel<<<(128 * 512 + 255) / 256, 256, 0, stream>>>(edge_W, Wcat);
    pack_wgru_kernel<<<(512 * 256 + 255) / 256, 256, 0, stream>>>(w_ih, w_hh, Wgru);

    // CSR build
    hist_kernel<<<(E + 255) / 256, 256, 0, stream>>>(dst, deg, E);
    scan_blocks_kernel<<<nb, 256, 0, stream>>>(deg, rowptr, blocksum, M);
    scan_top_kernel<<<1, 256, 0, stream>>>(blocksum, blockoff, nb);
    finalize_kernel<<<(M + 255) / 256, 256, 0, stream>>>(rowptr, blockoff, cursor, M);
    fill_kernel<<<(E + 255) / 256, 256, 0, stream>>>(src, dst, edge_type, cursor, csr, E);

    // S[n, t*128+:] = sum of same-type neighbor hbf rows; counts
    gather_s_kernel<<<(M + 3) / 4, 256, 0, stream>>>(rowptr, deg, csr, (const unsigned int*)hbf,
                                                     (float4*)cnt4, (unsigned int*)S, M);

    // aggbf = S @ Wcat^T + cnt*b   (K=512, S read once)
    agg_gemm<<<(M + 127) / 128, 256, 0, stream>>>(S, Wcat, (const float4*)cnt4, edge_b, aggbf, M);

    // fused GRU GEMM + gates -> out  (2 gate-halves, X read twice from LLC)
    dim3 ggrid((M + 63) / 64, 2);
    gemm_gru<<<ggrid, 256, 0, stream>>>(Wgru, aggbf, hbf, node_states, b_ih, b_hh,
                                        (float*)d_out, M);
}